// Round 7
// baseline (247.460 us; speedup 1.0000x reference)
//
#include <hip/hip_runtime.h>
#include <hip/hip_fp16.h>
#include <math.h>

typedef _Float16 h2_t __attribute__((ext_vector_type(2)));
typedef _Float16 h4_t __attribute__((ext_vector_type(4)));
typedef _Float16 h8_t __attribute__((ext_vector_type(8)));
typedef float f4_t __attribute__((ext_vector_type(4)));
typedef float f8_t __attribute__((ext_vector_type(8)));

#define PRE_BLOCKS 512
#define SB 512          // scatter/hist blocks (edge chunking)
#define NBUK_PAD 800    // padded bucket count; real buckets = (N+63)>>6 <= 782
#define CTB 16          // buckets per colscan block (64B per row -> line-aligned)

__device__ inline h8_t load8f_to_h8(const float* p) {
    float4 a = *(const float4*)p;
    float4 b = *(const float4*)(p + 4);
    h8_t r;
    r[0] = (_Float16)a.x; r[1] = (_Float16)a.y; r[2] = (_Float16)a.z; r[3] = (_Float16)a.w;
    r[4] = (_Float16)b.x; r[5] = (_Float16)b.y; r[6] = (_Float16)b.z; r[7] = (_Float16)b.w;
    return r;
}

__device__ inline h4_t load4f_to_h4(const float* p) {
    float4 a = *(const float4*)p;
    h4_t r;
    r[0] = (_Float16)a.x; r[1] = (_Float16)a.y; r[2] = (_Float16)a.z; r[3] = (_Float16)a.w;
    return r;
}

__device__ inline float dot8h(h8_t a, h8_t b, float s) {
    s = __builtin_amdgcn_fdot2(__builtin_shufflevector(a, a, 0, 1),
                               __builtin_shufflevector(b, b, 0, 1), s, false);
    s = __builtin_amdgcn_fdot2(__builtin_shufflevector(a, a, 2, 3),
                               __builtin_shufflevector(b, b, 2, 3), s, false);
    s = __builtin_amdgcn_fdot2(__builtin_shufflevector(a, a, 4, 5),
                               __builtin_shufflevector(b, b, 4, 5), s, false);
    s = __builtin_amdgcn_fdot2(__builtin_shufflevector(a, a, 6, 7),
                               __builtin_shufflevector(b, b, 6, 7), s, false);
    return s;
}

__device__ inline float dot4h(h4_t a, h4_t b, float s) {
    s = __builtin_amdgcn_fdot2(__builtin_shufflevector(a, a, 0, 1),
                               __builtin_shufflevector(b, b, 0, 1), s, false);
    s = __builtin_amdgcn_fdot2(__builtin_shufflevector(a, a, 2, 3),
                               __builtin_shufflevector(b, b, 2, 3), s, false);
    return s;
}

__device__ inline float elu1(float v) { return v > 0.f ? v : __expf(v) - 1.f; }

struct MA {
    const float* x;
    const float* eattr;
    const int* ei;
    const float *w1l, *b1l, *w1r, *b1r, *w1e, *att1, *bias1;
    const float *w2l, *b2l, *w2r, *b2r, *w2e, *att2, *bias2;
    const float *wc, *bc;
    float* out;
    _Float16 *xh, *xl1h, *xr1h, *h1h, *xl2h, *xr2h;
    _Float16 *p1l, *p1r, *p2l, *p2r;
    int *deg, *offb;
    unsigned* parth;      // SB x NBUK_PAD partial hist; after colscan: within-bucket excl prefix
    unsigned *tstart, *tot;
    unsigned* smeanq;
    unsigned* tmp;        // 4B packed: src[0:15] | q[16:23] | loc[24:29]
    float* part;
    unsigned* edges;
    int N, E, NW, NBK, CE;
    int n0node, n1node;   // node range for split k_node1 dispatches
    float invE;
};

// ---- phase helpers -------------------------------------------------------

__device__ inline void phase_packw(const MA& a, int g) {
    const float* W;
    _Float16* P;
    int M, lg;
    if (g < 2048)      { W = a.w1l; P = a.p1l; M = 128; lg = g; }
    else if (g < 4096) { W = a.w1r; P = a.p1r; M = 128; lg = g - 2048; }
    else if (g < 5120) { W = a.w2l; P = a.p2l; M = 64;  lg = g - 4096; }
    else               { W = a.w2r; P = a.p2r; M = 64;  lg = g - 5120; }
    int ln = lg & 63;
    int s = (lg >> 6) & 3;
    int tt = lg >> 8;
    int m = ln & 15, quad = ln >> 4;
    h8_t v;
#pragma unroll
    for (int j = 0; j < 8; ++j)
        v[j] = (_Float16)W[(size_t)(s * 32 + quad * 8 + j) * M + tt * 16 + m];
    *(h8_t*)(P + (size_t)lg * 8) = v;
}

template <int NT>
__device__ inline void phase_mm_tile(const MA& a, const _Float16* X, int rt, int lane,
                                     const _Float16* Pl, const float* bl, _Float16* Yl,
                                     const _Float16* Pr, const float* br, _Float16* Yr) {
    int nrow = lane & 15, quad = lane >> 4;
    int row = rt * 16 + nrow;
    if (row >= a.N) return;
    const _Float16* xp = X + (size_t)row * 128 + quad * 8;
    h8_t bf0 = *(const h8_t*)(xp);
    h8_t bf1 = *(const h8_t*)(xp + 32);
    h8_t bf2 = *(const h8_t*)(xp + 64);
    h8_t bf3 = *(const h8_t*)(xp + 96);
#pragma unroll
    for (int w = 0; w < 2; ++w) {
        const _Float16* P = w ? Pr : Pl;
        const float* bias = w ? br : bl;
        _Float16* Y = w ? Yr : Yl;
#pragma unroll
        for (int t2 = 0; t2 < NT; ++t2) {
            f4_t acc = {0.f, 0.f, 0.f, 0.f};
            const _Float16* pb = P + (size_t)t2 * 2048 + (size_t)lane * 8;
            acc = __builtin_amdgcn_mfma_f32_16x16x32_f16(*(const h8_t*)pb, bf0, acc, 0, 0, 0);
            acc = __builtin_amdgcn_mfma_f32_16x16x32_f16(*(const h8_t*)(pb + 512), bf1, acc, 0, 0, 0);
            acc = __builtin_amdgcn_mfma_f32_16x16x32_f16(*(const h8_t*)(pb + 1024), bf2, acc, 0, 0, 0);
            acc = __builtin_amdgcn_mfma_f32_16x16x32_f16(*(const h8_t*)(pb + 1536), bf3, acc, 0, 0, 0);
            float4 bv = *(const float4*)(bias + t2 * 16 + quad * 4);
            h4_t o;
            o[0] = (_Float16)(acc[0] + bv.x);
            o[1] = (_Float16)(acc[1] + bv.y);
            o[2] = (_Float16)(acc[2] + bv.z);
            o[3] = (_Float16)(acc[3] + bv.w);
            *(h4_t*)(Y + (size_t)row * (NT * 16) + t2 * 16 + quad * 4) = o;
        }
    }
}

// ---- k_pre: x->fp16, eattr partials, per-chunk bucket hist; tail blocks
// pack weights -------------------------------------------------------------

__global__ __launch_bounds__(256) void k_pre(MA a) {
    if (blockIdx.x >= PRE_BLOCKS) {
        int g = (blockIdx.x - PRE_BLOCKS) * 256 + threadIdx.x;
        if (g < 6144) phase_packw(a, g);
        return;
    }
    __shared__ unsigned bh[NBUK_PAD];
    __shared__ float sd[4];
    int tx = threadIdx.x;
    for (int j = tx; j < NBUK_PAD; j += 256) bh[j] = 0u;

    int t = blockIdx.x * 256 + tx;
    const int stride = PRE_BLOCKS * 256;
    int nchunk = (a.N * 128) >> 3;
    for (int i = t; i < nchunk; i += stride) {
        h8_t v = load8f_to_h8(a.x + (size_t)i * 8);
        *(h8_t*)(a.xh + (size_t)i * 8) = v;
    }
    float s = 0.f;
    for (int i = t; i < a.E; i += stride) s += a.eattr[i];
    for (int o = 1; o < 64; o <<= 1) s += __shfl_xor(s, o, 64);
    if ((tx & 63) == 0) sd[tx >> 6] = s;
    __syncthreads();  // bh zeroed + sd published
    if (tx == 0) a.part[blockIdx.x] = sd[0] + sd[1] + sd[2] + sd[3];

    // chunked bucket histogram (must match k_scatter's chunking exactly)
    int e0 = blockIdx.x * a.CE, e1 = min(e0 + a.CE, a.E);
    for (int e = e0 + tx; e < e1; e += 256)
        atomicAdd(&bh[((unsigned)a.ei[a.E + e]) >> 6], 1u);
    __syncthreads();
    for (int j = tx; j < NBUK_PAD; j += 256)
        a.parth[(size_t)blockIdx.x * NBUK_PAD + j] = bh[j];
}

// ---- k_colscan (R7 rewrite): 16-bucket tiles, line-aligned 64B per-thread
// loads (old version: 1 line per 4B value -> ~25MB effective for 1.6MB).
// Column scan = 16 row-rounds of width-32 warp scans; stride-17 LDS padding
// keeps rounds bank-conflict-free. Writes within-bucket exclusive prefix
// in place + tot[b]. ------------------------------------------------------

__global__ __launch_bounds__(512, 1) void k_colscan(MA a) {
    __shared__ unsigned tile[512][CTB + 1];
    int tx = threadIdx.x;
    int b0 = blockIdx.x * CTB;
    unsigned* rp = a.parth + (size_t)tx * NBUK_PAD + b0;
#pragma unroll
    for (int j = 0; j < CTB; ++j) tile[tx][j] = rp[j];
    __syncthreads();

    int c = tx >> 5;      // column 0..15 (2 columns per wave)
    int g = tx & 31;      // 32 threads per column
    unsigned base = 0;
#pragma unroll
    for (int k = 0; k < 16; ++k) {
        int r = k * 32 + g;           // rows [32k, 32k+32): contiguous round
        unsigned orig = tile[r][c];
        unsigned v = orig;
#pragma unroll
        for (int o = 1; o < 32; o <<= 1) {
            unsigned u = __shfl_up(v, o, 32);
            if (g >= o) v += u;
        }
        tile[r][c] = base + (v - orig);           // exclusive prefix
        base += __shfl(v, 31, 32);                // round total
    }
    if (g == 0) a.tot[b0 + c] = base;
    __syncthreads();
#pragma unroll
    for (int j = 0; j < CTB; ++j) rp[j] = tile[tx][j];
}

// ---- k_scan2: single block scans the <=1024 bucket totals -> tstart[],
// and reduces the eattr-mean partials -> smeanq. ---------------------------

__global__ __launch_bounds__(1024, 1) void k_scan2(MA a) {
    __shared__ unsigned lds[1024];
    __shared__ float sd[16];
    int tx = threadIdx.x;
    unsigned v = (tx < a.NBK) ? a.tot[tx] : 0u;
    lds[tx] = v;
    float s = (tx < PRE_BLOCKS) ? a.part[tx] : 0.f;
    for (int o = 1; o < 64; o <<= 1) s += __shfl_xor(s, o, 64);
    if ((tx & 63) == 0) sd[tx >> 6] = s;
    __syncthreads();
    for (int o = 1; o < 1024; o <<= 1) {
        unsigned u = (tx >= o) ? lds[tx - o] : 0u;
        __syncthreads();
        lds[tx] += u;
        __syncthreads();
    }
    if (tx < a.NBK) a.tstart[tx] = lds[tx] - v;
    if (tx == 0) {
        float m = 0.f;
#pragma unroll
        for (int k = 0; k < 16; ++k) m += sd[k];
        a.smeanq[0] = (unsigned)__float2int_rn(m * a.invE * 255.f);
    }
}

// ---- k_scatter: blocks [0,NW) = layer-1 GEMM; blocks [NW,NW+SB) scatter
// edges into coarse-bucket regions of tmp via LDS cursors (zero global
// atomics). cur = tstart[bucket] + within-bucket chunk base. --------------

__global__ __launch_bounds__(256) void k_scatter(MA a) {
    int bid = blockIdx.x;
    if (bid < a.NW) {
        int wid = bid * 4 + (threadIdx.x >> 6);
        int ntile = (a.N + 15) / 16;
        if (wid < ntile)
            phase_mm_tile<8>(a, a.xh, wid, threadIdx.x & 63,
                             a.p1l, a.b1l, a.xl1h, a.p1r, a.b1r, a.xr1h);
        return;
    }
    __shared__ unsigned cur[NBUK_PAD];
    int s = bid - a.NW;
    int tx = threadIdx.x;
    for (int j = tx; j < NBUK_PAD; j += 256)
        cur[j] = a.parth[(size_t)s * NBUK_PAD + j] + a.tstart[j];
    __syncthreads();
    int e0 = s * a.CE, e1 = min(e0 + a.CE, a.E);
    for (int e = e0 + tx; e < e1; e += 256) {
        int d = a.ei[a.E + e];
        unsigned src = (unsigned)a.ei[e];
        unsigned q = (unsigned)__float2int_rn(a.eattr[e] * 255.f);
        unsigned pos = atomicAdd(&cur[d >> 6], 1u);
        a.tmp[pos] = src | (q << 16) | ((unsigned)(d & 63) << 24);
    }
}

// ---- k_fine: per bucket (64 contiguous nodes): local hist + wave scan ->
// exact CSR offsets (no global scan needed), write self-loops + edges. ----

__global__ __launch_bounds__(256) void k_fine(MA a) {
    __shared__ int hist[64];
    __shared__ unsigned cur[64];
    __shared__ unsigned sm;
    int b = blockIdx.x;
    int tx = threadIdx.x;
    int n0 = b << 6;
    int nn = min(64, a.N - n0);
    unsigned ts = a.tstart[b], T = a.tot[b];
    if (tx < 64) hist[tx] = 0;
    if (tx == 0) sm = a.smeanq[0];
    __syncthreads();
    for (unsigned i = tx; i < T; i += 256) {
        unsigned v = a.tmp[ts + i];
        atomicAdd(&hist[(int)(v >> 24)], 1);
    }
    __syncthreads();
    if (tx < 64) {
        int deg1 = hist[tx] + 1;
        int vsc = deg1;
#pragma unroll
        for (int o = 1; o < 64; o <<= 1) {
            int u = __shfl_up(vsc, o, 64);
            if (tx >= o) vsc += u;
        }
        int off = (int)ts + n0 + (vsc - deg1);  // ts + 64*b accounts for prior self-loops
        if (tx < nn) {
            a.offb[n0 + tx] = off;
            a.deg[n0 + tx] = deg1;
            a.edges[off] = (unsigned)(n0 + tx) | (sm << 24);
        }
        cur[tx] = (unsigned)(off + 1);
    }
    __syncthreads();
    for (unsigned i = tx; i < T; i += 256) {
        unsigned v = a.tmp[ts + i];
        int loc = (int)(v >> 24);
        unsigned pos = atomicAdd(&cur[loc], 1u);
        a.edges[pos] = (v & 0xFFFFu) | (((v >> 16) & 0xFFu) << 24);
    }
}

// ---- k_node1: layer-1 node pass. 16 lanes per node, software-pipelined
// double buffer. Launched as TWO half-grids (n0node/n1node) so the #2
// kernel becomes visible in the top-5 profile. -----------------------------

__global__ __launch_bounds__(256) void k_node1(MA a) {
    int tid = threadIdx.x;
    int q = tid & 15;
    int node = a.n0node + blockIdx.x * 16 + (tid >> 4);
    if (node >= a.n1node) return;
    unsigned cb = (unsigned)(q * 16);  // byte offset of this lane's 8 halves

    h8_t xrv = *(const h8_t*)((const char*)a.xr1h + ((unsigned)node << 8) + cb);
    h8_t wev = load8f_to_h8(a.w1e + q * 8);
    h8_t atv = load8f_to_h8(a.att1 + q * 8);
    const unsigned* ep = a.edges + a.offb[node];
    int deg1 = a.deg[node];
    int last = deg1 - 1;
    const char* xb = (const char*)a.xl1h;

    float l = 0.f;
    f8_t acc = {0.f, 0.f, 0.f, 0.f, 0.f, 0.f, 0.f, 0.f};

    auto GA = [&](unsigned p) -> h8_t {
        return *(const h8_t*)(xb + (((p & 0x00FFFFFFu) << 8) | cb));
    };
    auto LOADG = [&](int i, unsigned& p0, unsigned& p1, unsigned& p2, unsigned& p3,
                     h8_t& x0, h8_t& x1, h8_t& x2, h8_t& x3) {
        p0 = ep[i];
        p1 = ep[min(i + 1, last)];
        p2 = ep[min(i + 2, last)];
        p3 = ep[min(i + 3, last)];
        x0 = GA(p0); x1 = GA(p1); x2 = GA(p2); x3 = GA(p3);
    };
    auto COMPG = [&](int i, unsigned p0, unsigned p1, unsigned p2, unsigned p3,
                     h8_t x0, h8_t x1, h8_t x2, h8_t x3) {
        float e0 = (float)(p0 >> 24) * (1.f / 255.f);
        float e1 = (float)(p1 >> 24) * (1.f / 255.f);
        float e2 = (float)(p2 >> 24) * (1.f / 255.f);
        float e3 = (float)(p3 >> 24) * (1.f / 255.f);
        h8_t z0 = x0 + xrv + wev * (_Float16)e0;
        z0 = __builtin_elementwise_max(z0, z0 * (_Float16)0.2f);
        float sc0 = dot8h(z0, atv, 0.f);
        h8_t z1 = x1 + xrv + wev * (_Float16)e1;
        z1 = __builtin_elementwise_max(z1, z1 * (_Float16)0.2f);
        float sc1 = dot8h(z1, atv, 0.f);
        h8_t z2 = x2 + xrv + wev * (_Float16)e2;
        z2 = __builtin_elementwise_max(z2, z2 * (_Float16)0.2f);
        float sc2 = dot8h(z2, atv, 0.f);
        h8_t z3 = x3 + xrv + wev * (_Float16)e3;
        z3 = __builtin_elementwise_max(z3, z3 * (_Float16)0.2f);
        float sc3 = dot8h(z3, atv, 0.f);
        sc0 += __shfl_xor(sc0, 1, 64); sc0 += __shfl_xor(sc0, 2, 64);
        sc1 += __shfl_xor(sc1, 1, 64); sc1 += __shfl_xor(sc1, 2, 64);
        sc2 += __shfl_xor(sc2, 1, 64); sc2 += __shfl_xor(sc2, 2, 64);
        sc3 += __shfl_xor(sc3, 1, 64); sc3 += __shfl_xor(sc3, 2, 64);
        float pA = __expf(fminf(sc0, 60.f));
        float pB = (i + 1 < deg1) ? __expf(fminf(sc1, 60.f)) : 0.f;
        float pC = (i + 2 < deg1) ? __expf(fminf(sc2, 60.f)) : 0.f;
        float pD = (i + 3 < deg1) ? __expf(fminf(sc3, 60.f)) : 0.f;
        l += (pA + pB) + (pC + pD);
#pragma unroll
        for (int k = 0; k < 8; ++k)
            acc[k] = fmaf(pA, (float)x0[k],
                     fmaf(pB, (float)x1[k],
                     fmaf(pC, (float)x2[k], fmaf(pD, (float)x3[k], acc[k]))));
    };

    unsigned pa0, pa1, pa2, pa3, pb0, pb1, pb2, pb3;
    h8_t xa0, xa1, xa2, xa3, xb0, xb1, xb2, xb3;
    LOADG(0, pa0, pa1, pa2, pa3, xa0, xa1, xa2, xa3);
    for (int i = 0; i < deg1; i += 8) {
        if (i + 4 < deg1) LOADG(i + 4, pb0, pb1, pb2, pb3, xb0, xb1, xb2, xb3);
        COMPG(i, pa0, pa1, pa2, pa3, xa0, xa1, xa2, xa3);
        if (i + 8 < deg1) LOADG(i + 8, pa0, pa1, pa2, pa3, xa0, xa1, xa2, xa3);
        if (i + 4 < deg1) COMPG(i + 4, pb0, pb1, pb2, pb3, xb0, xb1, xb2, xb3);
    }

    float inv = 1.f / l;
    float4 b0 = *(const float4*)(a.bias1 + q * 8);
    float4 b1 = *(const float4*)(a.bias1 + q * 8 + 4);
    float bb[8] = {b0.x, b0.y, b0.z, b0.w, b1.x, b1.y, b1.z, b1.w};
    h8_t o;
#pragma unroll
    for (int k = 0; k < 8; ++k) o[k] = (_Float16)elu1(fmaf(acc[k], inv, bb[k]));
    *(h8_t*)((char*)a.h1h + ((unsigned)node << 8) + cb) = o;
}

// ---- k_mm4: layer-2 MFMA GEMM --------------------------------------------

__global__ __launch_bounds__(256) void k_mm4(MA a) {
    int wid = blockIdx.x * 4 + (threadIdx.x >> 6);
    int ntile = (a.N + 15) / 16;
    if (wid >= ntile) return;
    phase_mm_tile<4>(a, a.h1h, wid, threadIdx.x & 63,
                     a.p2l, a.b2l, a.xl2h, a.p2r, a.b2r, a.xr2h);
}

// ---- k_node2: layer-2 node pass + fused classifier -----------------------

__global__ __launch_bounds__(256) void k_node2(MA a) {
    __shared__ float h2s[16][33];
    int tid = threadIdx.x;
    int lane = tid & 63;
    int wib = tid >> 6;
    int sub = lane >> 4;
    int r = lane & 15;
    int nloc = wib * 4 + sub;
    int node = blockIdx.x * 16 + nloc;
    int c0 = r * 4;

    if (node < a.N) {
        h4_t xrv = *(const h4_t*)(a.xr2h + (size_t)node * 64 + c0);
        h4_t wev = load4f_to_h4(a.w2e + c0);
        h4_t atv = load4f_to_h4(a.att2 + c0);
        const unsigned* ep = a.edges + a.offb[node];
        int deg1 = a.deg[node];
        int last = deg1 - 1;
        const char* xb = (const char*)a.xl2h;
        unsigned cb = (unsigned)(c0 * 2);
        float l = 0.f;
        float acc[4] = {0.f, 0.f, 0.f, 0.f};
        for (int i = 0; i < deg1; i += 4) {
            unsigned p[4];
            h4_t xv[4];
#pragma unroll
            for (int j = 0; j < 4; ++j) p[j] = ep[min(i + j, last)];
#pragma unroll
            for (int j = 0; j < 4; ++j)
                xv[j] = *(const h4_t*)(xb + (((p[j] & 0x00FFFFFFu) << 7) | cb));
#pragma unroll
            for (int j = 0; j < 4; ++j) {
                float ea = (float)(p[j] >> 24) * (1.f / 255.f);
                h4_t z = xv[j] + xrv + wev * (_Float16)ea;
                z = __builtin_elementwise_max(z, z * (_Float16)0.2f);
                float sc = dot4h(z, atv, 0.f);
                sc += __shfl_xor(sc, 1, 64);
                sc += __shfl_xor(sc, 2, 64);
                sc += __shfl_xor(sc, 4, 64);
                float pp = (i + j < deg1) ? __expf(fminf(sc, 60.f)) : 0.f;
                l += pp;
#pragma unroll
                for (int k = 0; k < 4; ++k) acc[k] = fmaf(pp, (float)xv[j][k], acc[k]);
            }
        }
        float inv = 1.f / l;
#pragma unroll
        for (int k = 0; k < 4; ++k) {
            float norm = acc[k] * inv;
            float other = __shfl_xor(norm, 8, 64);
            float v = 0.5f * (norm + other);
            if (r < 8) h2s[nloc][c0 + k] = elu1(v + a.bias2[c0 + k]);
        }
    }
    __syncthreads();
    if (tid < 128) {
        int n = tid >> 3, j = tid & 7;
        int gnode = blockIdx.x * 16 + n;
        if (gnode < a.N) {
            float acc = a.bc[j];
#pragma unroll 8
            for (int d = 0; d < 32; ++d) acc = fmaf(h2s[n][d], a.wc[d * 8 + j], acc);
            a.out[(size_t)gnode * 8 + j] = acc;
        }
    }
}

// ---- launch --------------------------------------------------------------

extern "C" void kernel_launch(void* const* d_in, const int* in_sizes, int n_in,
                              void* d_out, int out_size, void* d_ws, size_t ws_size,
                              hipStream_t stream) {
    const int N = in_sizes[0] / 128;
    const int E = in_sizes[2];
    const int tot = E + N;

    char* ws = (char*)d_ws;
    size_t o = 0;
    auto alloc = [&](size_t bytes) -> void* {
        void* p = ws + o;
        o += (bytes + 255) & ~(size_t)255;
        return p;
    };
    MA a;
    a.x     = (const float*)d_in[0];
    a.ei    = (const int*)d_in[1];
    a.eattr = (const float*)d_in[2];
    a.w1l = (const float*)d_in[3];  a.b1l = (const float*)d_in[4];
    a.w1r = (const float*)d_in[5];  a.b1r = (const float*)d_in[6];
    a.w1e = (const float*)d_in[7];  a.att1 = (const float*)d_in[8];
    a.bias1 = (const float*)d_in[9];
    a.w2l = (const float*)d_in[10]; a.b2l = (const float*)d_in[11];
    a.w2r = (const float*)d_in[12]; a.b2r = (const float*)d_in[13];
    a.w2e = (const float*)d_in[14]; a.att2 = (const float*)d_in[15];
    a.bias2 = (const float*)d_in[16];
    a.wc = (const float*)d_in[17];  a.bc = (const float*)d_in[18];
    a.out = (float*)d_out;

    a.xh   = (_Float16*)alloc((size_t)N * 128 * 2);
    a.xl1h = (_Float16*)alloc((size_t)N * 128 * 2);
    a.xr1h = (_Float16*)alloc((size_t)N * 128 * 2);
    a.h1h  = (_Float16*)alloc((size_t)N * 128 * 2);
    a.xl2h = (_Float16*)alloc((size_t)N * 64 * 2);
    a.xr2h = (_Float16*)alloc((size_t)N * 64 * 2);
    a.p1l  = (_Float16*)alloc(128 * 128 * 2);
    a.p1r  = (_Float16*)alloc(128 * 128 * 2);
    a.p2l  = (_Float16*)alloc(128 * 64 * 2);
    a.p2r  = (_Float16*)alloc(128 * 64 * 2);
    a.deg  = (int*)alloc((size_t)N * 4);
    a.offb = (int*)alloc((size_t)N * 4);
    a.parth  = (unsigned*)alloc((size_t)SB * NBUK_PAD * 4);
    a.tstart = (unsigned*)alloc(1024 * 4);
    a.tot    = (unsigned*)alloc(1024 * 4);
    a.smeanq = (unsigned*)alloc(256);
    a.part   = (float*)alloc(PRE_BLOCKS * 4);
    a.tmp    = (unsigned*)alloc((size_t)E * 4);
    a.edges  = (unsigned*)alloc((size_t)tot * 4);
    a.N = N;
    a.E = E;
    a.NW = (N + 63) / 64;
    a.NBK = (N + 63) >> 6;
    a.CE = (E + SB - 1) / SB;
    a.invE = 1.0f / (float)E;

    k_pre<<<PRE_BLOCKS + 24, 256, 0, stream>>>(a);
    k_colscan<<<NBUK_PAD / CTB, 512, 0, stream>>>(a);
    k_scan2<<<1, 1024, 0, stream>>>(a);
    k_scatter<<<a.NW + SB, 256, 0, stream>>>(a);
    k_fine<<<a.NBK, 256, 0, stream>>>(a);

    int mid = ((N / 2) + 15) & ~15;
    MA a1 = a; a1.n0node = 0;   a1.n1node = mid;
    MA a2 = a; a2.n0node = mid; a2.n1node = N;
    k_node1<<<mid / 16, 256, 0, stream>>>(a1);
    k_node1<<<(N - mid + 15) / 16, 256, 0, stream>>>(a2);

    k_mm4<<<(N + 63) / 64, 256, 0, stream>>>(a);
    k_node2<<<(N + 15) / 16, 256, 0, stream>>>(a);
}

// Round 8
// 241.765 us; speedup vs baseline: 1.0236x; 1.0236x over previous
//
#include <hip/hip_runtime.h>
#include <hip/hip_fp16.h>
#include <math.h>

typedef _Float16 h2_t __attribute__((ext_vector_type(2)));
typedef _Float16 h4_t __attribute__((ext_vector_type(4)));
typedef _Float16 h8_t __attribute__((ext_vector_type(8)));
typedef float f4_t __attribute__((ext_vector_type(4)));
typedef float f8_t __attribute__((ext_vector_type(8)));

#define PRE_BLOCKS 512
#define SB 512          // scatter/hist blocks (edge chunking)
#define NBUK_PAD 800    // padded bucket count; real buckets = (N+63)>>6 <= 782
#define CTB 16          // buckets per colscan block (64B per row -> line-aligned)

__device__ inline h8_t load8f_to_h8(const float* p) {
    float4 a = *(const float4*)p;
    float4 b = *(const float4*)(p + 4);
    h8_t r;
    r[0] = (_Float16)a.x; r[1] = (_Float16)a.y; r[2] = (_Float16)a.z; r[3] = (_Float16)a.w;
    r[4] = (_Float16)b.x; r[5] = (_Float16)b.y; r[6] = (_Float16)b.z; r[7] = (_Float16)b.w;
    return r;
}

__device__ inline h4_t load4f_to_h4(const float* p) {
    float4 a = *(const float4*)p;
    h4_t r;
    r[0] = (_Float16)a.x; r[1] = (_Float16)a.y; r[2] = (_Float16)a.z; r[3] = (_Float16)a.w;
    return r;
}

__device__ inline float dot8h(h8_t a, h8_t b, float s) {
    s = __builtin_amdgcn_fdot2(__builtin_shufflevector(a, a, 0, 1),
                               __builtin_shufflevector(b, b, 0, 1), s, false);
    s = __builtin_amdgcn_fdot2(__builtin_shufflevector(a, a, 2, 3),
                               __builtin_shufflevector(b, b, 2, 3), s, false);
    s = __builtin_amdgcn_fdot2(__builtin_shufflevector(a, a, 4, 5),
                               __builtin_shufflevector(b, b, 4, 5), s, false);
    s = __builtin_amdgcn_fdot2(__builtin_shufflevector(a, a, 6, 7),
                               __builtin_shufflevector(b, b, 6, 7), s, false);
    return s;
}

__device__ inline float dot4h(h4_t a, h4_t b, float s) {
    s = __builtin_amdgcn_fdot2(__builtin_shufflevector(a, a, 0, 1),
                               __builtin_shufflevector(b, b, 0, 1), s, false);
    s = __builtin_amdgcn_fdot2(__builtin_shufflevector(a, a, 2, 3),
                               __builtin_shufflevector(b, b, 2, 3), s, false);
    return s;
}

__device__ inline float elu1(float v) { return v > 0.f ? v : __expf(v) - 1.f; }

struct MA {
    const float* x;
    const float* eattr;
    const int* ei;
    const float *w1l, *b1l, *w1r, *b1r, *w1e, *att1, *bias1;
    const float *w2l, *b2l, *w2r, *b2r, *w2e, *att2, *bias2;
    const float *wc, *bc;
    float* out;
    _Float16 *xh, *xl1h, *xr1h, *xl2h, *xr2h;
    _Float16 *p1l, *p1r, *p2l, *p2r;
    int *deg, *offb;
    unsigned* parth;      // SB x NBUK_PAD partial hist; after colscan: within-bucket excl prefix
    unsigned* tot;        // per-bucket totals (from colscan)
    unsigned* tmp;        // 4B packed: src[0:15] | q[16:23] | loc[24:29]
    float* part;
    unsigned* edges;
    int N, E, NW, NBK, CE;
    float invE;
};

// ---- phase helpers -------------------------------------------------------

__device__ inline void phase_packw(const MA& a, int g) {
    const float* W;
    _Float16* P;
    int M, lg;
    if (g < 2048)      { W = a.w1l; P = a.p1l; M = 128; lg = g; }
    else if (g < 4096) { W = a.w1r; P = a.p1r; M = 128; lg = g - 2048; }
    else if (g < 5120) { W = a.w2l; P = a.p2l; M = 64;  lg = g - 4096; }
    else               { W = a.w2r; P = a.p2r; M = 64;  lg = g - 5120; }
    int ln = lg & 63;
    int s = (lg >> 6) & 3;
    int tt = lg >> 8;
    int m = ln & 15, quad = ln >> 4;
    h8_t v;
#pragma unroll
    for (int j = 0; j < 8; ++j)
        v[j] = (_Float16)W[(size_t)(s * 32 + quad * 8 + j) * M + tt * 16 + m];
    *(h8_t*)(P + (size_t)lg * 8) = v;
}

template <int NT>
__device__ inline void phase_mm_tile(const MA& a, const _Float16* X, int rt, int lane,
                                     const _Float16* Pl, const float* bl, _Float16* Yl,
                                     const _Float16* Pr, const float* br, _Float16* Yr) {
    int nrow = lane & 15, quad = lane >> 4;
    int row = rt * 16 + nrow;
    if (row >= a.N) return;
    const _Float16* xp = X + (size_t)row * 128 + quad * 8;
    h8_t bf0 = *(const h8_t*)(xp);
    h8_t bf1 = *(const h8_t*)(xp + 32);
    h8_t bf2 = *(const h8_t*)(xp + 64);
    h8_t bf3 = *(const h8_t*)(xp + 96);
#pragma unroll
    for (int w = 0; w < 2; ++w) {
        const _Float16* P = w ? Pr : Pl;
        const float* bias = w ? br : bl;
        _Float16* Y = w ? Yr : Yl;
#pragma unroll
        for (int t2 = 0; t2 < NT; ++t2) {
            f4_t acc = {0.f, 0.f, 0.f, 0.f};
            const _Float16* pb = P + (size_t)t2 * 2048 + (size_t)lane * 8;
            acc = __builtin_amdgcn_mfma_f32_16x16x32_f16(*(const h8_t*)pb, bf0, acc, 0, 0, 0);
            acc = __builtin_amdgcn_mfma_f32_16x16x32_f16(*(const h8_t*)(pb + 512), bf1, acc, 0, 0, 0);
            acc = __builtin_amdgcn_mfma_f32_16x16x32_f16(*(const h8_t*)(pb + 1024), bf2, acc, 0, 0, 0);
            acc = __builtin_amdgcn_mfma_f32_16x16x32_f16(*(const h8_t*)(pb + 1536), bf3, acc, 0, 0, 0);
            float4 bv = *(const float4*)(bias + t2 * 16 + quad * 4);
            h4_t o;
            o[0] = (_Float16)(acc[0] + bv.x);
            o[1] = (_Float16)(acc[1] + bv.y);
            o[2] = (_Float16)(acc[2] + bv.z);
            o[3] = (_Float16)(acc[3] + bv.w);
            *(h4_t*)(Y + (size_t)row * (NT * 16) + t2 * 16 + quad * 4) = o;
        }
    }
}

// ---- k_pre: x->fp16, eattr partials, per-chunk bucket hist; tail blocks
// pack weights -------------------------------------------------------------

__global__ __launch_bounds__(256) void k_pre(MA a) {
    if (blockIdx.x >= PRE_BLOCKS) {
        int g = (blockIdx.x - PRE_BLOCKS) * 256 + threadIdx.x;
        if (g < 6144) phase_packw(a, g);
        return;
    }
    __shared__ unsigned bh[NBUK_PAD];
    __shared__ float sd[4];
    int tx = threadIdx.x;
    for (int j = tx; j < NBUK_PAD; j += 256) bh[j] = 0u;

    int t = blockIdx.x * 256 + tx;
    const int stride = PRE_BLOCKS * 256;
    int nchunk = (a.N * 128) >> 3;
    for (int i = t; i < nchunk; i += stride) {
        h8_t v = load8f_to_h8(a.x + (size_t)i * 8);
        *(h8_t*)(a.xh + (size_t)i * 8) = v;
    }
    float s = 0.f;
    for (int i = t; i < a.E; i += stride) s += a.eattr[i];
    for (int o = 1; o < 64; o <<= 1) s += __shfl_xor(s, o, 64);
    if ((tx & 63) == 0) sd[tx >> 6] = s;
    __syncthreads();  // bh zeroed + sd published
    if (tx == 0) a.part[blockIdx.x] = sd[0] + sd[1] + sd[2] + sd[3];

    // chunked bucket histogram (must match k_scatter's chunking exactly)
    int e0 = blockIdx.x * a.CE, e1 = min(e0 + a.CE, a.E);
    for (int e = e0 + tx; e < e1; e += 256)
        atomicAdd(&bh[((unsigned)a.ei[a.E + e]) >> 6], 1u);
    __syncthreads();
    for (int j = tx; j < NBUK_PAD; j += 256)
        a.parth[(size_t)blockIdx.x * NBUK_PAD + j] = bh[j];
}

// ---- k_colscan: 16-bucket tiles, line-aligned 64B per-thread loads.
// Column scan = 16 row-rounds of width-32 warp scans. Writes within-bucket
// exclusive prefix in place + tot[b]. -------------------------------------

__global__ __launch_bounds__(512, 1) void k_colscan(MA a) {
    __shared__ unsigned tile[512][CTB + 1];
    int tx = threadIdx.x;
    int b0 = blockIdx.x * CTB;
    unsigned* rp = a.parth + (size_t)tx * NBUK_PAD + b0;
#pragma unroll
    for (int j = 0; j < CTB; ++j) tile[tx][j] = rp[j];
    __syncthreads();

    int c = tx >> 5;      // column 0..15 (2 columns per wave)
    int g = tx & 31;      // 32 threads per column
    unsigned base = 0;
#pragma unroll
    for (int k = 0; k < 16; ++k) {
        int r = k * 32 + g;           // rows [32k, 32k+32): contiguous round
        unsigned orig = tile[r][c];
        unsigned v = orig;
#pragma unroll
        for (int o = 1; o < 32; o <<= 1) {
            unsigned u = __shfl_up(v, o, 32);
            if (g >= o) v += u;
        }
        tile[r][c] = base + (v - orig);           // exclusive prefix
        base += __shfl(v, 31, 32);                // round total
    }
    if (g == 0) a.tot[b0 + c] = base;
    __syncthreads();
#pragma unroll
    for (int j = 0; j < CTB; ++j) rp[j] = tile[tx][j];
}

// ---- k_scatter: blocks [0,NW) = layer-1 GEMM; blocks [NW,NW+SB) scatter.
// Each scatter block scans tot[0..800) itself in LDS (removes the k_scan2
// dispatch; ~1us of parallel redundant work vs ~10us dispatch boundary). --

__global__ __launch_bounds__(256) void k_scatter(MA a) {
    int bid = blockIdx.x;
    if (bid < a.NW) {
        int wid = bid * 4 + (threadIdx.x >> 6);
        int ntile = (a.N + 15) / 16;
        if (wid < ntile)
            phase_mm_tile<8>(a, a.xh, wid, threadIdx.x & 63,
                             a.p1l, a.b1l, a.xl1h, a.p1r, a.b1r, a.xr1h);
        return;
    }
    __shared__ unsigned cur[1024];
    __shared__ unsigned wt[4];
    int s = bid - a.NW;
    int tx = threadIdx.x;
    // load totals (zeros beyond NBUK_PAD)
    for (int j = tx; j < 1024; j += 256)
        cur[j] = (j < NBUK_PAD) ? a.tot[j] : 0u;
    __syncthreads();
    // exclusive scan of 1024 values: 4 elems/thread + wave scan + wave offsets
    {
        unsigned x0 = cur[tx * 4], x1 = cur[tx * 4 + 1], x2 = cur[tx * 4 + 2], x3 = cur[tx * 4 + 3];
        unsigned s1 = x0 + x1, s2 = s1 + x2, t = s2 + x3;
        unsigned inc = t;
#pragma unroll
        for (int o = 1; o < 64; o <<= 1) {
            unsigned u = __shfl_up(inc, o, 64);
            if ((tx & 63) >= o) inc += u;
        }
        if ((tx & 63) == 63) wt[tx >> 6] = inc;
        __syncthreads();
        unsigned wb = 0;
#pragma unroll
        for (int k = 0; k < 4; ++k) wb += (k < (tx >> 6)) ? wt[k] : 0u;
        unsigned excl = wb + (inc - t);
        cur[tx * 4]     = excl;
        cur[tx * 4 + 1] = excl + x0;
        cur[tx * 4 + 2] = excl + s1;
        cur[tx * 4 + 3] = excl + s2;
    }
    __syncthreads();
    for (int j = tx; j < NBUK_PAD; j += 256)
        cur[j] += a.parth[(size_t)s * NBUK_PAD + j];
    __syncthreads();
    int e0 = s * a.CE, e1 = min(e0 + a.CE, a.E);
    for (int e = e0 + tx; e < e1; e += 256) {
        int d = a.ei[a.E + e];
        unsigned src = (unsigned)a.ei[e];
        unsigned q = (unsigned)__float2int_rn(a.eattr[e] * 255.f);
        unsigned pos = atomicAdd(&cur[d >> 6], 1u);
        a.tmp[pos] = src | (q << 16) | ((unsigned)(d & 63) << 24);
    }
}

// ---- k_fuse: per bucket (64 nodes): CSR build (fine) + layer-1 attention
// (node1, edges L2-warm) + layer-2 GEMM tiles from LDS-resident h1 (mm4).
// Collapses 3 dispatches into 1 and removes the h1h global round-trip. ----

__global__ __launch_bounds__(256) void k_fuse(MA a) {
    __shared__ int hist[64];
    __shared__ unsigned cur[64];
    __shared__ int offl[64], degl[64];
    __shared__ unsigned rts[4];
    __shared__ float rs[4];
    __shared__ _Float16 h1s[64 * 128];   // 16 KB: this bucket's h1 rows

    int b = blockIdx.x, tx = threadIdx.x;
    int n0 = b << 6;
    int nn = min(64, a.N - n0);

    if (tx < 64) hist[tx] = 0;
    // tstart[b] = sum tot[0..b)
    unsigned ps = 0;
    for (int j = tx; j < b; j += 256) ps += a.tot[j];
    for (int o = 1; o < 64; o <<= 1) ps += __shfl_xor(ps, o, 64);
    if ((tx & 63) == 0) rts[tx >> 6] = ps;
    // mean edge attr -> 8-bit quant
    float s = 0.f;
    for (int j = tx; j < PRE_BLOCKS; j += 256) s += a.part[j];
    for (int o = 1; o < 64; o <<= 1) s += __shfl_xor(s, o, 64);
    if ((tx & 63) == 0) rs[tx >> 6] = s;
    __syncthreads();
    unsigned ts = rts[0] + rts[1] + rts[2] + rts[3];
    unsigned sm = (unsigned)__float2int_rn((rs[0] + rs[1] + rs[2] + rs[3]) * a.invE * 255.f);
    unsigned T = a.tot[b];

    // ---- fine phase: local hist -> CSR offsets -> self-loops + scatter ----
    for (unsigned i = tx; i < T; i += 256)
        atomicAdd(&hist[(int)(a.tmp[ts + i] >> 24)], 1);
    __syncthreads();
    if (tx < 64) {
        int deg1 = hist[tx] + 1;
        int vsc = deg1;
#pragma unroll
        for (int o = 1; o < 64; o <<= 1) {
            int u = __shfl_up(vsc, o, 64);
            if (tx >= o) vsc += u;
        }
        int off = (int)ts + n0 + (vsc - deg1);
        if (tx < nn) {
            a.offb[n0 + tx] = off;
            a.deg[n0 + tx] = deg1;
            a.edges[off] = (unsigned)(n0 + tx) | (sm << 24);
            offl[tx] = off;
            degl[tx] = deg1;
        }
        cur[tx] = (unsigned)(off + 1);
    }
    __syncthreads();
    for (unsigned i = tx; i < T; i += 256) {
        unsigned v = a.tmp[ts + i];
        unsigned pos = atomicAdd(&cur[v >> 24], 1u);
        a.edges[pos] = (v & 0xFFFFu) | (((v >> 16) & 0xFFu) << 24);
    }
    __syncthreads();

    // ---- node1 phase: 16 lanes/node, 16 nodes/round, 4 rounds -------------
    int q = tx & 15;
    unsigned cb = (unsigned)(q * 16);
    h8_t wev = load8f_to_h8(a.w1e + q * 8);
    h8_t atv = load8f_to_h8(a.att1 + q * 8);
    float4 bv0 = *(const float4*)(a.bias1 + q * 8);
    float4 bv1 = *(const float4*)(a.bias1 + q * 8 + 4);
    float bb[8] = {bv0.x, bv0.y, bv0.z, bv0.w, bv1.x, bv1.y, bv1.z, bv1.w};
    const char* xb = (const char*)a.xl1h;

    for (int rr = 0; rr < 64; rr += 16) {
        int nloc = rr + (tx >> 4);
        if (nloc < nn) {
            int node = n0 + nloc;
            h8_t xrv = *(const h8_t*)((const char*)a.xr1h + ((unsigned)node << 8) + cb);
            const unsigned* ep = a.edges + offl[nloc];
            int deg1 = degl[nloc];
            int last = deg1 - 1;
            float l = 0.f;
            f8_t acc = {0.f, 0.f, 0.f, 0.f, 0.f, 0.f, 0.f, 0.f};

            auto GA = [&](unsigned p) -> h8_t {
                return *(const h8_t*)(xb + (((p & 0x00FFFFFFu) << 8) | cb));
            };
            auto LOADG = [&](int i, unsigned& p0, unsigned& p1, unsigned& p2, unsigned& p3,
                             h8_t& x0, h8_t& x1, h8_t& x2, h8_t& x3) {
                p0 = ep[i];
                p1 = ep[min(i + 1, last)];
                p2 = ep[min(i + 2, last)];
                p3 = ep[min(i + 3, last)];
                x0 = GA(p0); x1 = GA(p1); x2 = GA(p2); x3 = GA(p3);
            };
            auto COMPG = [&](int i, unsigned p0, unsigned p1, unsigned p2, unsigned p3,
                             h8_t x0, h8_t x1, h8_t x2, h8_t x3) {
                float e0 = (float)(p0 >> 24) * (1.f / 255.f);
                float e1 = (float)(p1 >> 24) * (1.f / 255.f);
                float e2 = (float)(p2 >> 24) * (1.f / 255.f);
                float e3 = (float)(p3 >> 24) * (1.f / 255.f);
                h8_t z0 = x0 + xrv + wev * (_Float16)e0;
                z0 = __builtin_elementwise_max(z0, z0 * (_Float16)0.2f);
                float sc0 = dot8h(z0, atv, 0.f);
                h8_t z1 = x1 + xrv + wev * (_Float16)e1;
                z1 = __builtin_elementwise_max(z1, z1 * (_Float16)0.2f);
                float sc1 = dot8h(z1, atv, 0.f);
                h8_t z2 = x2 + xrv + wev * (_Float16)e2;
                z2 = __builtin_elementwise_max(z2, z2 * (_Float16)0.2f);
                float sc2 = dot8h(z2, atv, 0.f);
                h8_t z3 = x3 + xrv + wev * (_Float16)e3;
                z3 = __builtin_elementwise_max(z3, z3 * (_Float16)0.2f);
                float sc3 = dot8h(z3, atv, 0.f);
                sc0 += __shfl_xor(sc0, 1, 64); sc0 += __shfl_xor(sc0, 2, 64);
                sc1 += __shfl_xor(sc1, 1, 64); sc1 += __shfl_xor(sc1, 2, 64);
                sc2 += __shfl_xor(sc2, 1, 64); sc2 += __shfl_xor(sc2, 2, 64);
                sc3 += __shfl_xor(sc3, 1, 64); sc3 += __shfl_xor(sc3, 2, 64);
                float pA = __expf(fminf(sc0, 60.f));
                float pB = (i + 1 < deg1) ? __expf(fminf(sc1, 60.f)) : 0.f;
                float pC = (i + 2 < deg1) ? __expf(fminf(sc2, 60.f)) : 0.f;
                float pD = (i + 3 < deg1) ? __expf(fminf(sc3, 60.f)) : 0.f;
                l += (pA + pB) + (pC + pD);
#pragma unroll
                for (int k = 0; k < 8; ++k)
                    acc[k] = fmaf(pA, (float)x0[k],
                             fmaf(pB, (float)x1[k],
                             fmaf(pC, (float)x2[k], fmaf(pD, (float)x3[k], acc[k]))));
            };

            unsigned pa0, pa1, pa2, pa3, pb0, pb1, pb2, pb3;
            h8_t xa0, xa1, xa2, xa3, xb0, xb1, xb2, xb3;
            LOADG(0, pa0, pa1, pa2, pa3, xa0, xa1, xa2, xa3);
            for (int i = 0; i < deg1; i += 8) {
                if (i + 4 < deg1) LOADG(i + 4, pb0, pb1, pb2, pb3, xb0, xb1, xb2, xb3);
                COMPG(i, pa0, pa1, pa2, pa3, xa0, xa1, xa2, xa3);
                if (i + 8 < deg1) LOADG(i + 8, pa0, pa1, pa2, pa3, xa0, xa1, xa2, xa3);
                if (i + 4 < deg1) COMPG(i + 4, pb0, pb1, pb2, pb3, xb0, xb1, xb2, xb3);
            }

            float inv = 1.f / l;
            h8_t o;
#pragma unroll
            for (int k = 0; k < 8; ++k) o[k] = (_Float16)elu1(fmaf(acc[k], inv, bb[k]));
            *(h8_t*)(h1s + nloc * 128 + q * 8) = o;
        }
    }
    __syncthreads();

    // ---- mm4 phase: 4 tiles x 16 rows, h1 read from LDS -------------------
    {
        int wv = tx >> 6, lane = tx & 63;
        int nrow = lane & 15, quad = lane >> 4;
        int row = n0 + wv * 16 + nrow;
        if (row < a.N) {
            const _Float16* xp = h1s + (wv * 16 + nrow) * 128 + quad * 8;
            h8_t bf0 = *(const h8_t*)(xp);
            h8_t bf1 = *(const h8_t*)(xp + 32);
            h8_t bf2 = *(const h8_t*)(xp + 64);
            h8_t bf3 = *(const h8_t*)(xp + 96);
#pragma unroll
            for (int w = 0; w < 2; ++w) {
                const _Float16* P = w ? a.p2r : a.p2l;
                const float* bias = w ? a.b2r : a.b2l;
                _Float16* Y = w ? a.xr2h : a.xl2h;
#pragma unroll
                for (int t2 = 0; t2 < 4; ++t2) {
                    f4_t acc2 = {0.f, 0.f, 0.f, 0.f};
                    const _Float16* pb = P + (size_t)t2 * 2048 + (size_t)lane * 8;
                    acc2 = __builtin_amdgcn_mfma_f32_16x16x32_f16(*(const h8_t*)pb, bf0, acc2, 0, 0, 0);
                    acc2 = __builtin_amdgcn_mfma_f32_16x16x32_f16(*(const h8_t*)(pb + 512), bf1, acc2, 0, 0, 0);
                    acc2 = __builtin_amdgcn_mfma_f32_16x16x32_f16(*(const h8_t*)(pb + 1024), bf2, acc2, 0, 0, 0);
                    acc2 = __builtin_amdgcn_mfma_f32_16x16x32_f16(*(const h8_t*)(pb + 1536), bf3, acc2, 0, 0, 0);
                    float4 bv = *(const float4*)(bias + t2 * 16 + quad * 4);
                    h4_t o;
                    o[0] = (_Float16)(acc2[0] + bv.x);
                    o[1] = (_Float16)(acc2[1] + bv.y);
                    o[2] = (_Float16)(acc2[2] + bv.z);
                    o[3] = (_Float16)(acc2[3] + bv.w);
                    *(h4_t*)(Y + (size_t)row * 64 + t2 * 16 + quad * 4) = o;
                }
            }
        }
    }
}

// ---- k_node2: layer-2 node pass + fused classifier -----------------------

__global__ __launch_bounds__(256) void k_node2(MA a) {
    __shared__ float h2s[16][33];
    int tid = threadIdx.x;
    int lane = tid & 63;
    int wib = tid >> 6;
    int sub = lane >> 4;
    int r = lane & 15;
    int nloc = wib * 4 + sub;
    int node = blockIdx.x * 16 + nloc;
    int c0 = r * 4;

    if (node < a.N) {
        h4_t xrv = *(const h4_t*)(a.xr2h + (size_t)node * 64 + c0);
        h4_t wev = load4f_to_h4(a.w2e + c0);
        h4_t atv = load4f_to_h4(a.att2 + c0);
        const unsigned* ep = a.edges + a.offb[node];
        int deg1 = a.deg[node];
        int last = deg1 - 1;
        const char* xb = (const char*)a.xl2h;
        unsigned cb = (unsigned)(c0 * 2);
        float l = 0.f;
        float acc[4] = {0.f, 0.f, 0.f, 0.f};
        for (int i = 0; i < deg1; i += 4) {
            unsigned p[4];
            h4_t xv[4];
#pragma unroll
            for (int j = 0; j < 4; ++j) p[j] = ep[min(i + j, last)];
#pragma unroll
            for (int j = 0; j < 4; ++j)
                xv[j] = *(const h4_t*)(xb + (((p[j] & 0x00FFFFFFu) << 7) | cb));
#pragma unroll
            for (int j = 0; j < 4; ++j) {
                float ea = (float)(p[j] >> 24) * (1.f / 255.f);
                h4_t z = xv[j] + xrv + wev * (_Float16)ea;
                z = __builtin_elementwise_max(z, z * (_Float16)0.2f);
                float sc = dot4h(z, atv, 0.f);
                sc += __shfl_xor(sc, 1, 64);
                sc += __shfl_xor(sc, 2, 64);
                sc += __shfl_xor(sc, 4, 64);
                float pp = (i + j < deg1) ? __expf(fminf(sc, 60.f)) : 0.f;
                l += pp;
#pragma unroll
                for (int k = 0; k < 4; ++k) acc[k] = fmaf(pp, (float)xv[j][k], acc[k]);
            }
        }
        float inv = 1.f / l;
#pragma unroll
        for (int k = 0; k < 4; ++k) {
            float norm = acc[k] * inv;
            float other = __shfl_xor(norm, 8, 64);
            float v = 0.5f * (norm + other);
            if (r < 8) h2s[nloc][c0 + k] = elu1(v + a.bias2[c0 + k]);
        }
    }
    __syncthreads();
    if (tid < 128) {
        int n = tid >> 3, j = tid & 7;
        int gnode = blockIdx.x * 16 + n;
        if (gnode < a.N) {
            float acc = a.bc[j];
#pragma unroll 8
            for (int d = 0; d < 32; ++d) acc = fmaf(h2s[n][d], a.wc[d * 8 + j], acc);
            a.out[(size_t)gnode * 8 + j] = acc;
        }
    }
}

// ---- launch --------------------------------------------------------------

extern "C" void kernel_launch(void* const* d_in, const int* in_sizes, int n_in,
                              void* d_out, int out_size, void* d_ws, size_t ws_size,
                              hipStream_t stream) {
    const int N = in_sizes[0] / 128;
    const int E = in_sizes[2];
    const int tot = E + N;

    char* ws = (char*)d_ws;
    size_t o = 0;
    auto alloc = [&](size_t bytes) -> void* {
        void* p = ws + o;
        o += (bytes + 255) & ~(size_t)255;
        return p;
    };
    MA a;
    a.x     = (const float*)d_in[0];
    a.ei    = (const int*)d_in[1];
    a.eattr = (const float*)d_in[2];
    a.w1l = (const float*)d_in[3];  a.b1l = (const float*)d_in[4];
    a.w1r = (const float*)d_in[5];  a.b1r = (const float*)d_in[6];
    a.w1e = (const float*)d_in[7];  a.att1 = (const float*)d_in[8];
    a.bias1 = (const float*)d_in[9];
    a.w2l = (const float*)d_in[10]; a.b2l = (const float*)d_in[11];
    a.w2r = (const float*)d_in[12]; a.b2r = (const float*)d_in[13];
    a.w2e = (const float*)d_in[14]; a.att2 = (const float*)d_in[15];
    a.bias2 = (const float*)d_in[16];
    a.wc = (const float*)d_in[17];  a.bc = (const float*)d_in[18];
    a.out = (float*)d_out;

    a.xh   = (_Float16*)alloc((size_t)N * 128 * 2);
    a.xl1h = (_Float16*)alloc((size_t)N * 128 * 2);
    a.xr1h = (_Float16*)alloc((size_t)N * 128 * 2);
    a.xl2h = (_Float16*)alloc((size_t)N * 64 * 2);
    a.xr2h = (_Float16*)alloc((size_t)N * 64 * 2);
    a.p1l  = (_Float16*)alloc(128 * 128 * 2);
    a.p1r  = (_Float16*)alloc(128 * 128 * 2);
    a.p2l  = (_Float16*)alloc(128 * 64 * 2);
    a.p2r  = (_Float16*)alloc(128 * 64 * 2);
    a.deg  = (int*)alloc((size_t)N * 4);
    a.offb = (int*)alloc((size_t)N * 4);
    a.parth = (unsigned*)alloc((size_t)SB * NBUK_PAD * 4);
    a.tot   = (unsigned*)alloc(1024 * 4);
    a.part  = (float*)alloc(PRE_BLOCKS * 4);
    a.tmp   = (unsigned*)alloc((size_t)E * 4);
    a.edges = (unsigned*)alloc((size_t)tot * 4);
    a.N = N;
    a.E = E;
    a.NW = (N + 63) / 64;
    a.NBK = (N + 63) >> 6;
    a.CE = (E + SB - 1) / SB;
    a.invE = 1.0f / (float)E;

    k_pre<<<PRE_BLOCKS + 24, 256, 0, stream>>>(a);
    k_colscan<<<NBUK_PAD / CTB, 512, 0, stream>>>(a);
    k_scatter<<<a.NW + SB, 256, 0, stream>>>(a);
    k_fuse<<<a.NBK, 256, 0, stream>>>(a);
    k_node2<<<(N + 15) / 16, 256, 0, stream>>>(a);
}

// Round 9
// 232.765 us; speedup vs baseline: 1.0631x; 1.0387x over previous
//
#include <hip/hip_runtime.h>
#include <hip/hip_fp16.h>
#include <math.h>

typedef _Float16 h2_t __attribute__((ext_vector_type(2)));
typedef _Float16 h4_t __attribute__((ext_vector_type(4)));
typedef _Float16 h8_t __attribute__((ext_vector_type(8)));
typedef float f4_t __attribute__((ext_vector_type(4)));
typedef float f8_t __attribute__((ext_vector_type(8)));

#define PRE_BLOCKS 512
#define SB 512          // scatter/hist blocks (edge chunking)
#define NBUK_PAD 800    // padded bucket count; real buckets = (N+63)>>6 <= 782
#define CTB 16          // buckets per colscan block (64B per row -> line-aligned)

__device__ inline h8_t load8f_to_h8(const float* p) {
    float4 a = *(const float4*)p;
    float4 b = *(const float4*)(p + 4);
    h8_t r;
    r[0] = (_Float16)a.x; r[1] = (_Float16)a.y; r[2] = (_Float16)a.z; r[3] = (_Float16)a.w;
    r[4] = (_Float16)b.x; r[5] = (_Float16)b.y; r[6] = (_Float16)b.z; r[7] = (_Float16)b.w;
    return r;
}

__device__ inline h4_t load4f_to_h4(const float* p) {
    float4 a = *(const float4*)p;
    h4_t r;
    r[0] = (_Float16)a.x; r[1] = (_Float16)a.y; r[2] = (_Float16)a.z; r[3] = (_Float16)a.w;
    return r;
}

__device__ inline float dot8h(h8_t a, h8_t b, float s) {
    s = __builtin_amdgcn_fdot2(__builtin_shufflevector(a, a, 0, 1),
                               __builtin_shufflevector(b, b, 0, 1), s, false);
    s = __builtin_amdgcn_fdot2(__builtin_shufflevector(a, a, 2, 3),
                               __builtin_shufflevector(b, b, 2, 3), s, false);
    s = __builtin_amdgcn_fdot2(__builtin_shufflevector(a, a, 4, 5),
                               __builtin_shufflevector(b, b, 4, 5), s, false);
    s = __builtin_amdgcn_fdot2(__builtin_shufflevector(a, a, 6, 7),
                               __builtin_shufflevector(b, b, 6, 7), s, false);
    return s;
}

__device__ inline float dot4h(h4_t a, h4_t b, float s) {
    s = __builtin_amdgcn_fdot2(__builtin_shufflevector(a, a, 0, 1),
                               __builtin_shufflevector(b, b, 0, 1), s, false);
    s = __builtin_amdgcn_fdot2(__builtin_shufflevector(a, a, 2, 3),
                               __builtin_shufflevector(b, b, 2, 3), s, false);
    return s;
}

__device__ inline float elu1(float v) { return v > 0.f ? v : __expf(v) - 1.f; }

struct MA {
    const float* x;
    const float* eattr;
    const int* ei;
    const float *w1l, *b1l, *w1r, *b1r, *w1e, *att1, *bias1;
    const float *w2l, *b2l, *w2r, *b2r, *w2e, *att2, *bias2;
    const float *wc, *bc;
    float* out;
    _Float16 *xh, *xl1h, *xr1h, *xl2h, *xr2h;
    _Float16 *p1l, *p1r, *p2l, *p2r;
    int *deg, *offb;
    unsigned* parth;      // SB x NBUK_PAD partial hist; after colscan: within-bucket excl prefix
    unsigned* tot;        // per-bucket totals (from colscan)
    unsigned *tstart, *smeanq;
    unsigned* tmp;        // 4B packed: src[0:15] | q[16:23] | loc[24:29]
    float* part;
    unsigned* edges;
    int N, E, NW, NBK, CE;
    float invE;
};

// ---- phase helpers -------------------------------------------------------

__device__ inline void phase_packw(const MA& a, int g) {
    const float* W;
    _Float16* P;
    int M, lg;
    if (g < 2048)      { W = a.w1l; P = a.p1l; M = 128; lg = g; }
    else if (g < 4096) { W = a.w1r; P = a.p1r; M = 128; lg = g - 2048; }
    else if (g < 5120) { W = a.w2l; P = a.p2l; M = 64;  lg = g - 4096; }
    else               { W = a.w2r; P = a.p2r; M = 64;  lg = g - 5120; }
    int ln = lg & 63;
    int s = (lg >> 6) & 3;
    int tt = lg >> 8;
    int m = ln & 15, quad = ln >> 4;
    h8_t v;
#pragma unroll
    for (int j = 0; j < 8; ++j)
        v[j] = (_Float16)W[(size_t)(s * 32 + quad * 8 + j) * M + tt * 16 + m];
    *(h8_t*)(P + (size_t)lg * 8) = v;
}

template <int NT>
__device__ inline void phase_mm_tile(const MA& a, const _Float16* X, int rt, int lane,
                                     const _Float16* Pl, const float* bl, _Float16* Yl,
                                     const _Float16* Pr, const float* br, _Float16* Yr) {
    int nrow = lane & 15, quad = lane >> 4;
    int row = rt * 16 + nrow;
    if (row >= a.N) return;
    const _Float16* xp = X + (size_t)row * 128 + quad * 8;
    h8_t bf0 = *(const h8_t*)(xp);
    h8_t bf1 = *(const h8_t*)(xp + 32);
    h8_t bf2 = *(const h8_t*)(xp + 64);
    h8_t bf3 = *(const h8_t*)(xp + 96);
#pragma unroll
    for (int w = 0; w < 2; ++w) {
        const _Float16* P = w ? Pr : Pl;
        const float* bias = w ? br : bl;
        _Float16* Y = w ? Yr : Yl;
#pragma unroll
        for (int t2 = 0; t2 < NT; ++t2) {
            f4_t acc = {0.f, 0.f, 0.f, 0.f};
            const _Float16* pb = P + (size_t)t2 * 2048 + (size_t)lane * 8;
            acc = __builtin_amdgcn_mfma_f32_16x16x32_f16(*(const h8_t*)pb, bf0, acc, 0, 0, 0);
            acc = __builtin_amdgcn_mfma_f32_16x16x32_f16(*(const h8_t*)(pb + 512), bf1, acc, 0, 0, 0);
            acc = __builtin_amdgcn_mfma_f32_16x16x32_f16(*(const h8_t*)(pb + 1024), bf2, acc, 0, 0, 0);
            acc = __builtin_amdgcn_mfma_f32_16x16x32_f16(*(const h8_t*)(pb + 1536), bf3, acc, 0, 0, 0);
            float4 bv = *(const float4*)(bias + t2 * 16 + quad * 4);
            h4_t o;
            o[0] = (_Float16)(acc[0] + bv.x);
            o[1] = (_Float16)(acc[1] + bv.y);
            o[2] = (_Float16)(acc[2] + bv.z);
            o[3] = (_Float16)(acc[3] + bv.w);
            *(h4_t*)(Y + (size_t)row * (NT * 16) + t2 * 16 + quad * 4) = o;
        }
    }
}

// ---- k_pre ---------------------------------------------------------------

__global__ __launch_bounds__(256) void k_pre(MA a) {
    if (blockIdx.x >= PRE_BLOCKS) {
        int g = (blockIdx.x - PRE_BLOCKS) * 256 + threadIdx.x;
        if (g < 6144) phase_packw(a, g);
        return;
    }
    __shared__ unsigned bh[NBUK_PAD];
    __shared__ float sd[4];
    int tx = threadIdx.x;
    for (int j = tx; j < NBUK_PAD; j += 256) bh[j] = 0u;

    int t = blockIdx.x * 256 + tx;
    const int stride = PRE_BLOCKS * 256;
    int nchunk = (a.N * 128) >> 3;
    for (int i = t; i < nchunk; i += stride) {
        h8_t v = load8f_to_h8(a.x + (size_t)i * 8);
        *(h8_t*)(a.xh + (size_t)i * 8) = v;
    }
    float s = 0.f;
    for (int i = t; i < a.E; i += stride) s += a.eattr[i];
    for (int o = 1; o < 64; o <<= 1) s += __shfl_xor(s, o, 64);
    if ((tx & 63) == 0) sd[tx >> 6] = s;
    __syncthreads();
    if (tx == 0) a.part[blockIdx.x] = sd[0] + sd[1] + sd[2] + sd[3];

    int e0 = blockIdx.x * a.CE, e1 = min(e0 + a.CE, a.E);
    for (int e = e0 + tx; e < e1; e += 256)
        atomicAdd(&bh[((unsigned)a.ei[a.E + e]) >> 6], 1u);
    __syncthreads();
    for (int j = tx; j < NBUK_PAD; j += 256)
        a.parth[(size_t)blockIdx.x * NBUK_PAD + j] = bh[j];
}

// ---- k_colscan: coalesced 16-bucket tiles --------------------------------

__global__ __launch_bounds__(512, 1) void k_colscan(MA a) {
    __shared__ unsigned tile[512][CTB + 1];
    int tx = threadIdx.x;
    int b0 = blockIdx.x * CTB;
    unsigned* rp = a.parth + (size_t)tx * NBUK_PAD + b0;
#pragma unroll
    for (int j = 0; j < CTB; ++j) tile[tx][j] = rp[j];
    __syncthreads();

    int c = tx >> 5;
    int g = tx & 31;
    unsigned base = 0;
#pragma unroll
    for (int k = 0; k < 16; ++k) {
        int r = k * 32 + g;
        unsigned orig = tile[r][c];
        unsigned v = orig;
#pragma unroll
        for (int o = 1; o < 32; o <<= 1) {
            unsigned u = __shfl_up(v, o, 32);
            if (g >= o) v += u;
        }
        tile[r][c] = base + (v - orig);
        base += __shfl(v, 31, 32);
    }
    if (g == 0) a.tot[b0 + c] = base;
    __syncthreads();
#pragma unroll
    for (int j = 0; j < CTB; ++j) rp[j] = tile[tx][j];
}

// ---- k_scatter: GEMM blocks + scatter blocks (inline scan of tot) --------

__global__ __launch_bounds__(256) void k_scatter(MA a) {
    int bid = blockIdx.x;
    if (bid < a.NW) {
        int wid = bid * 4 + (threadIdx.x >> 6);
        int ntile = (a.N + 15) / 16;
        if (wid < ntile)
            phase_mm_tile<8>(a, a.xh, wid, threadIdx.x & 63,
                             a.p1l, a.b1l, a.xl1h, a.p1r, a.b1r, a.xr1h);
        return;
    }
    __shared__ unsigned cur[1024];
    __shared__ unsigned wt[4];
    int s = bid - a.NW;
    int tx = threadIdx.x;
    for (int j = tx; j < 1024; j += 256)
        cur[j] = (j < NBUK_PAD) ? a.tot[j] : 0u;
    __syncthreads();
    {
        unsigned x0 = cur[tx * 4], x1 = cur[tx * 4 + 1], x2 = cur[tx * 4 + 2], x3 = cur[tx * 4 + 3];
        unsigned s1 = x0 + x1, s2 = s1 + x2, t = s2 + x3;
        unsigned inc = t;
#pragma unroll
        for (int o = 1; o < 64; o <<= 1) {
            unsigned u = __shfl_up(inc, o, 64);
            if ((tx & 63) >= o) inc += u;
        }
        if ((tx & 63) == 63) wt[tx >> 6] = inc;
        __syncthreads();
        unsigned wb = 0;
#pragma unroll
        for (int k = 0; k < 4; ++k) wb += (k < (tx >> 6)) ? wt[k] : 0u;
        unsigned excl = wb + (inc - t);
        cur[tx * 4]     = excl;
        cur[tx * 4 + 1] = excl + x0;
        cur[tx * 4 + 2] = excl + s1;
        cur[tx * 4 + 3] = excl + s2;
        // scatter block 0 publishes tstart + smean for k_fine
        if (s == 0) {
            if (tx < NBUK_PAD / 4) {
                a.tstart[tx * 4]     = cur[tx * 4];
                a.tstart[tx * 4 + 1] = cur[tx * 4 + 1];
                a.tstart[tx * 4 + 2] = cur[tx * 4 + 2];
                a.tstart[tx * 4 + 3] = cur[tx * 4 + 3];
            }
        }
    }
    __syncthreads();
    if (s == 0) {
        float ss = 0.f;
        for (int j = tx; j < PRE_BLOCKS; j += 256) ss += a.part[j];
        for (int o = 1; o < 64; o <<= 1) ss += __shfl_xor(ss, o, 64);
        __shared__ float rs[4];
        if ((tx & 63) == 0) rs[tx >> 6] = ss;
        __syncthreads();
        if (tx == 0)
            a.smeanq[0] = (unsigned)__float2int_rn((rs[0] + rs[1] + rs[2] + rs[3]) * a.invE * 255.f);
    }
    for (int j = tx; j < NBUK_PAD; j += 256)
        cur[j] += a.parth[(size_t)s * NBUK_PAD + j];
    __syncthreads();
    int e0 = s * a.CE, e1 = min(e0 + a.CE, a.E);
    for (int e = e0 + tx; e < e1; e += 256) {
        int d = a.ei[a.E + e];
        unsigned src = (unsigned)a.ei[e];
        unsigned q = (unsigned)__float2int_rn(a.eattr[e] * 255.f);
        unsigned pos = atomicAdd(&cur[d >> 6], 1u);
        a.tmp[pos] = src | (q << 16) | ((unsigned)(d & 63) << 24);
    }
}

// ---- k_fine: per bucket CSR build + self-loops + edge placement ----------

__global__ __launch_bounds__(256) void k_fine(MA a) {
    __shared__ int hist[64];
    __shared__ unsigned cur[64];
    __shared__ unsigned sm;
    int b = blockIdx.x;
    int tx = threadIdx.x;
    int n0 = b << 6;
    int nn = min(64, a.N - n0);
    unsigned ts = a.tstart[b], T = a.tot[b];
    if (tx < 64) hist[tx] = 0;
    if (tx == 0) sm = a.smeanq[0];
    __syncthreads();
    for (unsigned i = tx; i < T; i += 256) {
        unsigned v = a.tmp[ts + i];
        atomicAdd(&hist[(int)(v >> 24)], 1);
    }
    __syncthreads();
    if (tx < 64) {
        int deg1 = hist[tx] + 1;
        int vsc = deg1;
#pragma unroll
        for (int o = 1; o < 64; o <<= 1) {
            int u = __shfl_up(vsc, o, 64);
            if (tx >= o) vsc += u;
        }
        int off = (int)ts + n0 + (vsc - deg1);
        if (tx < nn) {
            a.offb[n0 + tx] = off;
            a.deg[n0 + tx] = deg1;
            a.edges[off] = (unsigned)(n0 + tx) | (sm << 24);
        }
        cur[tx] = (unsigned)(off + 1);
    }
    __syncthreads();
    for (unsigned i = tx; i < T; i += 256) {
        unsigned v = a.tmp[ts + i];
        int loc = (int)(v >> 24);
        unsigned pos = atomicAdd(&cur[loc], 1u);
        a.edges[pos] = (v & 0xFFFFu) | (((v >> 16) & 0xFFu) << 24);
    }
}

// ---- k_n1mm: layer-1 attention (16 nodes/block, full TLP, pipelined,
// tail-predicated gathers) + layer-2 GEMM on the block's 16 h1 rows via
// 4KB LDS (h1h never hits global; R8 lesson: fuse only at TLP-preserving
// granularity). ------------------------------------------------------------

__global__ __launch_bounds__(256) void k_n1mm(MA a) {
    __shared__ _Float16 h1s[16 * 128];   // 4 KB
    int tid = threadIdx.x;
    int q = tid & 15;
    int nloc = tid >> 4;
    int node = blockIdx.x * 16 + nloc;
    unsigned cb = (unsigned)(q * 16);

    if (node < a.N) {
        h8_t xrv = *(const h8_t*)((const char*)a.xr1h + ((unsigned)node << 8) + cb);
        h8_t wev = load8f_to_h8(a.w1e + q * 8);
        h8_t atv = load8f_to_h8(a.att1 + q * 8);
        const unsigned* ep = a.edges + a.offb[node];
        int deg1 = a.deg[node];
        int last = deg1 - 1;
        const char* xb = (const char*)a.xl1h;

        float l = 0.f;
        f8_t acc = {0.f, 0.f, 0.f, 0.f, 0.f, 0.f, 0.f, 0.f};

        auto GA = [&](unsigned p, bool valid) -> h8_t {
            h8_t r = {};
            if (valid) r = *(const h8_t*)(xb + (((p & 0x00FFFFFFu) << 8) | cb));
            return r;
        };
        auto LOADG = [&](int i, unsigned& p0, unsigned& p1, unsigned& p2, unsigned& p3,
                         h8_t& x0, h8_t& x1, h8_t& x2, h8_t& x3) {
            p0 = ep[i];
            p1 = ep[min(i + 1, last)];
            p2 = ep[min(i + 2, last)];
            p3 = ep[min(i + 3, last)];
            x0 = GA(p0, true);
            x1 = GA(p1, i + 1 < deg1);
            x2 = GA(p2, i + 2 < deg1);
            x3 = GA(p3, i + 3 < deg1);
        };
        auto COMPG = [&](int i, unsigned p0, unsigned p1, unsigned p2, unsigned p3,
                         h8_t x0, h8_t x1, h8_t x2, h8_t x3) {
            float e0 = (float)(p0 >> 24) * (1.f / 255.f);
            float e1 = (float)(p1 >> 24) * (1.f / 255.f);
            float e2 = (float)(p2 >> 24) * (1.f / 255.f);
            float e3 = (float)(p3 >> 24) * (1.f / 255.f);
            h8_t z0 = x0 + xrv + wev * (_Float16)e0;
            z0 = __builtin_elementwise_max(z0, z0 * (_Float16)0.2f);
            float sc0 = dot8h(z0, atv, 0.f);
            h8_t z1 = x1 + xrv + wev * (_Float16)e1;
            z1 = __builtin_elementwise_max(z1, z1 * (_Float16)0.2f);
            float sc1 = dot8h(z1, atv, 0.f);
            h8_t z2 = x2 + xrv + wev * (_Float16)e2;
            z2 = __builtin_elementwise_max(z2, z2 * (_Float16)0.2f);
            float sc2 = dot8h(z2, atv, 0.f);
            h8_t z3 = x3 + xrv + wev * (_Float16)e3;
            z3 = __builtin_elementwise_max(z3, z3 * (_Float16)0.2f);
            float sc3 = dot8h(z3, atv, 0.f);
            sc0 += __shfl_xor(sc0, 1, 64); sc0 += __shfl_xor(sc0, 2, 64);
            sc1 += __shfl_xor(sc1, 1, 64); sc1 += __shfl_xor(sc1, 2, 64);
            sc2 += __shfl_xor(sc2, 1, 64); sc2 += __shfl_xor(sc2, 2, 64);
            sc3 += __shfl_xor(sc3, 1, 64); sc3 += __shfl_xor(sc3, 2, 64);
            float pA = __expf(fminf(sc0, 60.f));
            float pB = (i + 1 < deg1) ? __expf(fminf(sc1, 60.f)) : 0.f;
            float pC = (i + 2 < deg1) ? __expf(fminf(sc2, 60.f)) : 0.f;
            float pD = (i + 3 < deg1) ? __expf(fminf(sc3, 60.f)) : 0.f;
            l += (pA + pB) + (pC + pD);
#pragma unroll
            for (int k = 0; k < 8; ++k)
                acc[k] = fmaf(pA, (float)x0[k],
                         fmaf(pB, (float)x1[k],
                         fmaf(pC, (float)x2[k], fmaf(pD, (float)x3[k], acc[k]))));
        };

        unsigned pa0, pa1, pa2, pa3, pb0, pb1, pb2, pb3;
        h8_t xa0, xa1, xa2, xa3, xb0, xb1, xb2, xb3;
        LOADG(0, pa0, pa1, pa2, pa3, xa0, xa1, xa2, xa3);
        for (int i = 0; i < deg1; i += 8) {
            if (i + 4 < deg1) LOADG(i + 4, pb0, pb1, pb2, pb3, xb0, xb1, xb2, xb3);
            COMPG(i, pa0, pa1, pa2, pa3, xa0, xa1, xa2, xa3);
            if (i + 8 < deg1) LOADG(i + 8, pa0, pa1, pa2, pa3, xa0, xa1, xa2, xa3);
            if (i + 4 < deg1) COMPG(i + 4, pb0, pb1, pb2, pb3, xb0, xb1, xb2, xb3);
        }

        float inv = 1.f / l;
        float4 b0 = *(const float4*)(a.bias1 + q * 8);
        float4 b1 = *(const float4*)(a.bias1 + q * 8 + 4);
        float bb[8] = {b0.x, b0.y, b0.z, b0.w, b1.x, b1.y, b1.z, b1.w};
        h8_t o;
#pragma unroll
        for (int k = 0; k < 8; ++k) o[k] = (_Float16)elu1(fmaf(acc[k], inv, bb[k]));
        *(h8_t*)(h1s + nloc * 128 + q * 8) = o;
    }
    __syncthreads();

    // mm4 phase: 8 (l/r x t2) tile-tasks split over 4 waves, h1 from LDS
    {
        int wv = tid >> 6, lane = tid & 63;
        int nrow = lane & 15, quad = lane >> 4;
        int row = blockIdx.x * 16 + nrow;
        if (row < a.N) {
            const _Float16* xp = h1s + nrow * 128 + quad * 8;
            h8_t bf0 = *(const h8_t*)(xp);
            h8_t bf1 = *(const h8_t*)(xp + 32);
            h8_t bf2 = *(const h8_t*)(xp + 64);
            h8_t bf3 = *(const h8_t*)(xp + 96);
#pragma unroll
            for (int k = 0; k < 2; ++k) {
                int idx = wv * 2 + k;
                int w = idx >> 2, t2 = idx & 3;
                const _Float16* P = w ? a.p2r : a.p2l;
                const float* bias = w ? a.b2r : a.b2l;
                _Float16* Y = w ? a.xr2h : a.xl2h;
                f4_t acc2 = {0.f, 0.f, 0.f, 0.f};
                const _Float16* pb = P + (size_t)t2 * 2048 + (size_t)lane * 8;
                acc2 = __builtin_amdgcn_mfma_f32_16x16x32_f16(*(const h8_t*)pb, bf0, acc2, 0, 0, 0);
                acc2 = __builtin_amdgcn_mfma_f32_16x16x32_f16(*(const h8_t*)(pb + 512), bf1, acc2, 0, 0, 0);
                acc2 = __builtin_amdgcn_mfma_f32_16x16x32_f16(*(const h8_t*)(pb + 1024), bf2, acc2, 0, 0, 0);
                acc2 = __builtin_amdgcn_mfma_f32_16x16x32_f16(*(const h8_t*)(pb + 1536), bf3, acc2, 0, 0, 0);
                float4 bv = *(const float4*)(bias + t2 * 16 + quad * 4);
                h4_t o;
                o[0] = (_Float16)(acc2[0] + bv.x);
                o[1] = (_Float16)(acc2[1] + bv.y);
                o[2] = (_Float16)(acc2[2] + bv.z);
                o[3] = (_Float16)(acc2[3] + bv.w);
                *(h4_t*)(Y + (size_t)row * 64 + t2 * 16 + quad * 4) = o;
            }
        }
    }
}

// ---- k_node2: layer-2 node pass + fused classifier (tail-predicated) -----

__global__ __launch_bounds__(256) void k_node2(MA a) {
    __shared__ float h2s[16][33];
    int tid = threadIdx.x;
    int lane = tid & 63;
    int wib = tid >> 6;
    int sub = lane >> 4;
    int r = lane & 15;
    int nloc = wib * 4 + sub;
    int node = blockIdx.x * 16 + nloc;
    int c0 = r * 4;

    if (node < a.N) {
        h4_t xrv = *(const h4_t*)(a.xr2h + (size_t)node * 64 + c0);
        h4_t wev = load4f_to_h4(a.w2e + c0);
        h4_t atv = load4f_to_h4(a.att2 + c0);
        const unsigned* ep = a.edges + a.offb[node];
        int deg1 = a.deg[node];
        int last = deg1 - 1;
        const char* xb = (const char*)a.xl2h;
        unsigned cb = (unsigned)(c0 * 2);
        float l = 0.f;
        float acc[4] = {0.f, 0.f, 0.f, 0.f};
        for (int i = 0; i < deg1; i += 4) {
            unsigned p[4];
            h4_t xv[4];
#pragma unroll
            for (int j = 0; j < 4; ++j) p[j] = ep[min(i + j, last)];
#pragma unroll
            for (int j = 0; j < 4; ++j) {
                xv[j] = h4_t{};
                if (i + j < deg1)
                    xv[j] = *(const h4_t*)(xb + (((p[j] & 0x00FFFFFFu) << 7) | cb));
            }
#pragma unroll
            for (int j = 0; j < 4; ++j) {
                float ea = (float)(p[j] >> 24) * (1.f / 255.f);
                h4_t z = xv[j] + xrv + wev * (_Float16)ea;
                z = __builtin_elementwise_max(z, z * (_Float16)0.2f);
                float sc = dot4h(z, atv, 0.f);
                sc += __shfl_xor(sc, 1, 64);
                sc += __shfl_xor(sc, 2, 64);
                sc += __shfl_xor(sc, 4, 64);
                float pp = (i + j < deg1) ? __expf(fminf(sc, 60.f)) : 0.f;
                l += pp;
#pragma unroll
                for (int k = 0; k < 4; ++k) acc[k] = fmaf(pp, (float)xv[j][k], acc[k]);
            }
        }
        float inv = 1.f / l;
#pragma unroll
        for (int k = 0; k < 4; ++k) {
            float norm = acc[k] * inv;
            float other = __shfl_xor(norm, 8, 64);
            float v = 0.5f * (norm + other);
            if (r < 8) h2s[nloc][c0 + k] = elu1(v + a.bias2[c0 + k]);
        }
    }
    __syncthreads();
    if (tid < 128) {
        int n = tid >> 3, j = tid & 7;
        int gnode = blockIdx.x * 16 + n;
        if (gnode < a.N) {
            float acc = a.bc[j];
#pragma unroll 8
            for (int d = 0; d < 32; ++d) acc = fmaf(h2s[n][d], a.wc[d * 8 + j], acc);
            a.out[(size_t)gnode * 8 + j] = acc;
        }
    }
}

// ---- launch --------------------------------------------------------------

extern "C" void kernel_launch(void* const* d_in, const int* in_sizes, int n_in,
                              void* d_out, int out_size, void* d_ws, size_t ws_size,
                              hipStream_t stream) {
    const int N = in_sizes[0] / 128;
    const int E = in_sizes[2];
    const int tot = E + N;

    char* ws = (char*)d_ws;
    size_t o = 0;
    auto alloc = [&](size_t bytes) -> void* {
        void* p = ws + o;
        o += (bytes + 255) & ~(size_t)255;
        return p;
    };
    MA a;
    a.x     = (const float*)d_in[0];
    a.ei    = (const int*)d_in[1];
    a.eattr = (const float*)d_in[2];
    a.w1l = (const float*)d_in[3];  a.b1l = (const float*)d_in[4];
    a.w1r = (const float*)d_in[5];  a.b1r = (const float*)d_in[6];
    a.w1e = (const float*)d_in[7];  a.att1 = (const float*)d_in[8];
    a.bias1 = (const float*)d_in[9];
    a.w2l = (const float*)d_in[10]; a.b2l = (const float*)d_in[11];
    a.w2r = (const float*)d_in[12]; a.b2r = (const float*)d_in[13];
    a.w2e = (const float*)d_in[14]; a.att2 = (const float*)d_in[15];
    a.bias2 = (const float*)d_in[16];
    a.wc = (const float*)d_in[17];  a.bc = (const float*)d_in[18];
    a.out = (float*)d_out;

    a.xh   = (_Float16*)alloc((size_t)N * 128 * 2);
    a.xl1h = (_Float16*)alloc((size_t)N * 128 * 2);
    a.xr1h = (_Float16*)alloc((size_t)N * 128 * 2);
    a.xl2h = (_Float16*)alloc((size_t)N * 64 * 2);
    a.xr2h = (_Float16*)alloc((size_t)N * 64 * 2);
    a.p1l  = (_Float16*)alloc(128 * 128 * 2);
    a.p1r  = (_Float16*)alloc(128 * 128 * 2);
    a.p2l  = (_Float16*)alloc(128 * 64 * 2);
    a.p2r  = (_Float16*)alloc(128 * 64 * 2);
    a.deg  = (int*)alloc((size_t)N * 4);
    a.offb = (int*)alloc((size_t)N * 4);
    a.parth  = (unsigned*)alloc((size_t)SB * NBUK_PAD * 4);
    a.tot    = (unsigned*)alloc(1024 * 4);
    a.tstart = (unsigned*)alloc(1024 * 4);
    a.smeanq = (unsigned*)alloc(256);
    a.part   = (float*)alloc(PRE_BLOCKS * 4);
    a.tmp    = (unsigned*)alloc((size_t)E * 4);
    a.edges  = (unsigned*)alloc((size_t)tot * 4);
    a.N = N;
    a.E = E;
    a.NW = (N + 63) / 64;
    a.NBK = (N + 63) >> 6;
    a.CE = (E + SB - 1) / SB;
    a.invE = 1.0f / (float)E;

    k_pre<<<PRE_BLOCKS + 24, 256, 0, stream>>>(a);
    k_colscan<<<NBUK_PAD / CTB, 512, 0, stream>>>(a);
    k_scatter<<<a.NW + SB, 256, 0, stream>>>(a);
    k_fine<<<a.NBK, 256, 0, stream>>>(a);
    k_n1mm<<<(N + 15) / 16, 256, 0, stream>>>(a);
    k_node2<<<(N + 15) / 16, 256, 0, stream>>>(a);
}